// Round 14
// baseline (184.435 us; speedup 1.0000x reference)
//
#include <hip/hip_runtime.h>

typedef __attribute__((ext_vector_type(8))) short bf16x8;
typedef __attribute__((ext_vector_type(4))) float f32x4;

#define GAMMA_ 0.5f
#define LOG2E_ 1.4426950408889634f

constexpr int D      = 256;   // feature dim (K)
constexpr int BM     = 128;   // rows of X per block (2 row-groups of 64)
constexpr int JSPLIT = 8;     // split of M across blockIdx.y

// LDS layout (bytes):
//   [0, 65536)      : per-wave B rings, wave w at [w*16384, +16K): 4 slots x 4KB
//   [65536, 69632)  : tcol panel (1024 x f32)
//   [69632, 73728)  : coef panel (1024 x f32)
//   [73728, 74240)  : srow panel (128 x f32)
constexpr int AUX_TCOL  = 65536;
constexpr int AUX_COEF  = 69632;
constexpr int AUX_SROW  = 73728;
constexpr int LDS_BYTES = 74240;

// ---------- helpers ----------
__device__ __forceinline__ unsigned short f2bf(float f) {
    unsigned int x = __float_as_uint(f);
    x += 0x7FFFu + ((x >> 16) & 1u);          // RNE
    return (unsigned short)(x >> 16);
}

__device__ __forceinline__ void gload16(void* lds, const void* g) {
    __builtin_amdgcn_global_load_lds(
        (const __attribute__((address_space(1))) void*)g,
        (__attribute__((address_space(3))) void*)lds, 16, 0, 0);
}

// ---------- prep ----------
// A rows: linear bf16 [row][k].  B rows: packed DMA/MFMA-native layout:
//   stage block (gjt,kt,wc) = 4KB at ((gjt*4+kt)*2+wc)*4096, inside:
//   chunk c = ni*2+ks (1KB), element (hi*16+lo)*16 + half*8
//   holding bf16x8 of (col = gjt*64+wc*32+ni*16+lo, k = kt*64+ks*32+hi*8..+8)
__global__ void prep_all_kernel(const float* __restrict__ X,
                                const float* __restrict__ Xt,
                                const float* __restrict__ alphas,
                                const float* __restrict__ y,
                                const float* __restrict__ b,
                                unsigned short* __restrict__ Abf,
                                char* __restrict__ Bws,
                                float* __restrict__ srow,
                                float* __restrict__ tcol,
                                float* __restrict__ coef,
                                float* __restrict__ out,
                                int N, int M) {
    int w = threadIdx.x >> 6;         // one wave per row
    int l = threadIdx.x & 63;
    int row = blockIdx.x * 4 + w;
    if (row >= N + M) return;

    const float* src = (row < N) ? X + (size_t)row * D
                                 : Xt + (size_t)(row - N) * D;
    const float4 v = reinterpret_cast<const float4*>(src)[l];
    ushort4 u;
    u.x = f2bf(v.x); u.y = f2bf(v.y); u.z = f2bf(v.z); u.w = f2bf(v.w);

    if (row < N) {
        reinterpret_cast<ushort4*>(Abf + (size_t)row * D)[l] = u;
    } else {
        int r2  = row - N;
        int gjt = r2 >> 6, wcp = (r2 >> 5) & 1, nip = (r2 >> 4) & 1, lop = r2 & 15;
        int ktp = l >> 4, ksp = (l >> 3) & 1, hip = (l >> 1) & 3, half = l & 1;
        size_t dst = ((size_t)(gjt * 4 + ktp) * 2 + wcp) * 4096
                   + (size_t)(nip * 2 + ksp) * 1024 + (hip * 16 + lop) * 16
                   + half * 8;
        *reinterpret_cast<ushort4*>(Bws + dst) = u;
    }

    float ss = v.x * v.x + v.y * v.y + v.z * v.z + v.w * v.w;
    #pragma unroll
    for (int off = 32; off >= 1; off >>= 1) ss += __shfl_xor(ss, off);
    if (l == 0) {
        float folded = -GAMMA_ * LOG2E_ * ss;
        if (row < N) { srow[row] = folded; out[row] = b[0]; }
        else {
            int r2 = row - N;
            tcol[r2] = folded;
            coef[r2] = alphas[r2] * y[r2];
        }
    }
}

// ---------- fused RBF-SVM predict: linear-DMA wave-private pipeline ----------
// pred_i = sum_j exp2( s_i + t_j + (2*g*log2e) * <x_i, xt_j> ) * coef_j + b
// Wave (wr,wc): rows [wr*64,+64), cols = wc-half of each 64-col tile.
// B pre-packed so each stage is ONE contiguous 4KB block: linear DMA source,
// linear LDS dest, ds_read = base + l*16 (+imm) -> no swizzle, no conflicts.
// 4-slot ring, 3 stages in flight, counted vmcnt(12), NO barriers in loop.
__launch_bounds__(256, 2)
__global__ void svm_main_kernel(const unsigned short* __restrict__ Abf,
                                const char* __restrict__ Bws,
                                const float* __restrict__ srow,
                                const float* __restrict__ tcol,
                                const float* __restrict__ coef,
                                float* __restrict__ out,
                                int M) {
    __shared__ char L[LDS_BYTES];

    const int tid = threadIdx.x;
    const int w   = tid >> 6;          // wave 0..3
    const int l   = tid & 63;
    const int wr  = w >> 1;            // row group 0..1
    const int wc  = w & 1;             // col half 0..1 (wave-private cols)
    const int hi  = l >> 4;            // 0..3
    const int lo  = l & 15;
    const int row0   = blockIdx.x * BM;
    const int jspan  = M / JSPLIT;     // 1024
    const int jbase  = blockIdx.y * jspan;
    const int NS     = (jspan / 64) * 4;   // 64 stages (16 jt x 4 kt)

    // ---- aux staging (shared; drained before the loop) ----
    gload16(L + AUX_TCOL + w * 1024, (const char*)(tcol + jbase) + tid * 16);
    gload16(L + AUX_COEF + w * 1024, (const char*)(coef + jbase) + tid * 16);
    if (w == 0 && l < 32)
        gload16(L + AUX_SROW, (const char*)(srow + row0) + l * 16);

    // ---- A strip into registers (held whole kernel) ----
    const char* Ab = (const char*)Abf;
    bf16x8 areg[4][8];
    #pragma unroll
    for (int mi = 0; mi < 4; ++mi) {
        int row = row0 + wr * 64 + mi * 16 + lo;
        #pragma unroll
        for (int kg = 0; kg < 8; ++kg)
            areg[mi][kg] = *(const bf16x8*)(Ab + (size_t)row * 512 + kg * 64 + hi * 16);
    }

    asm volatile("s_waitcnt vmcnt(0)" ::: "memory");   // drain ALL pre-loop VMEM
    __builtin_amdgcn_s_barrier();                      // aux visible; last barrier

    // per-lane row constants from LDS aux
    float sreg[4][4];
    #pragma unroll
    for (int mi = 0; mi < 4; ++mi)
        #pragma unroll
        for (int r = 0; r < 4; ++r)
            sreg[mi][r] = *(const float*)(L + AUX_SROW
                            + (wr * 64 + mi * 16 + hi * 4 + r) * 4);

    // ---- wave-private B ring: stage = contiguous 4KB, 4 linear gload16 ----
    const char* Bst = Bws + ((size_t)(jbase >> 6) * 8) * 4096 + (size_t)wc * 4096;
    const int   ring0 = w * 16384;
    auto issueB = [&](int s) {
        const char* src = Bst + (size_t)s * 8192 + l * 16;
        char* dst = L + ring0 + (s & 3) * 4096;        // wave-uniform base
        #pragma unroll
        for (int c = 0; c < 4; ++c)
            gload16(dst + c * 1024, src + c * 1024);
    };
    issueB(0);
    issueB(1);
    issueB(2);   // 12 outstanding (3 stages deep)

    float partial[4][4];
    #pragma unroll
    for (int mi = 0; mi < 4; ++mi)
        #pragma unroll
        for (int r = 0; r < 4; ++r) partial[mi][r] = 0.0f;

    const float K2G = 2.0f * GAMMA_ * LOG2E_;
    const int cb0 = wc * 32;
    f32x4 acc[4][2];

    for (int s = 0; s < NS; ++s) {
        const int kt = s & 3;

        if (kt == 0) {
            #pragma unroll
            for (int mi = 0; mi < 4; ++mi)
                #pragma unroll
                for (int ni = 0; ni < 2; ++ni) {
                    f32x4 z = {0.f, 0.f, 0.f, 0.f};
                    acc[mi][ni] = z;
                }
        }

        // issue stage s+3; counted wait completes stage s (never 0 mid-loop)
        if (s + 3 < NS) {
            issueB(s + 3);
            asm volatile("s_waitcnt vmcnt(12)" ::: "memory");
        } else if (s == NS - 3) {
            asm volatile("s_waitcnt vmcnt(8)" ::: "memory");
        } else if (s == NS - 2) {
            asm volatile("s_waitcnt vmcnt(4)" ::: "memory");
        } else {
            asm volatile("s_waitcnt vmcnt(0)" ::: "memory");
        }

        // ---- 4 conflict-free ds_read_b128 (base + l*16, imm offsets) ----
        const char* p = L + ring0 + (s & 3) * 4096 + l * 16;
        bf16x8 bb00 = *(const bf16x8*)(p);           // ni=0 ks=0
        bf16x8 bb01 = *(const bf16x8*)(p + 1024);    // ni=0 ks=1
        bf16x8 bb10 = *(const bf16x8*)(p + 2048);    // ni=1 ks=0
        bf16x8 bb11 = *(const bf16x8*)(p + 3072);    // ni=1 ks=1

        __builtin_amdgcn_s_setprio(1);
        #pragma unroll
        for (int mi = 0; mi < 4; ++mi) {
            acc[mi][0] = __builtin_amdgcn_mfma_f32_16x16x32_bf16(
                areg[mi][kt * 2 + 0], bb00, acc[mi][0], 0, 0, 0);
            acc[mi][1] = __builtin_amdgcn_mfma_f32_16x16x32_bf16(
                areg[mi][kt * 2 + 0], bb10, acc[mi][1], 0, 0, 0);
        }
        #pragma unroll
        for (int mi = 0; mi < 4; ++mi) {
            acc[mi][0] = __builtin_amdgcn_mfma_f32_16x16x32_bf16(
                areg[mi][kt * 2 + 1], bb01, acc[mi][0], 0, 0, 0);
            acc[mi][1] = __builtin_amdgcn_mfma_f32_16x16x32_bf16(
                areg[mi][kt * 2 + 1], bb11, acc[mi][1], 0, 0, 0);
        }
        __builtin_amdgcn_s_setprio(0);

        // ---- per-j-tile fused epilogue: exp2 + weighted row-accumulate ----
        if (kt == 3) {
            const int jt = s >> 2;
            #pragma unroll
            for (int ni = 0; ni < 2; ++ni) {
                int cl = jt * 64 + cb0 + ni * 16 + lo;
                float t  = *(const float*)(L + AUX_TCOL + cl * 4);
                float cf = *(const float*)(L + AUX_COEF + cl * 4);
                #pragma unroll
                for (int mi = 0; mi < 4; ++mi) {
                    #pragma unroll
                    for (int r = 0; r < 4; ++r) {
                        float arg = fmaf(acc[mi][ni][r], K2G, sreg[mi][r] + t);
                        float p2 = __builtin_amdgcn_exp2f(arg);
                        partial[mi][r] = fmaf(p2, cf, partial[mi][r]);
                    }
                }
            }
        }
    }

    // ---- reduce across the 16 lanes of each row group, one atomic per row ----
    #pragma unroll
    for (int mi = 0; mi < 4; ++mi) {
        #pragma unroll
        for (int r = 0; r < 4; ++r) {
            float v = partial[mi][r];
            v += __shfl_xor(v, 1);
            v += __shfl_xor(v, 2);
            v += __shfl_xor(v, 4);
            v += __shfl_xor(v, 8);
            if (lo == 0) {
                int rowg = row0 + wr * 64 + mi * 16 + hi * 4 + r;
                atomicAdd(&out[rowg], v);
            }
        }
    }
}

// ---------- launcher ----------
extern "C" void kernel_launch(void* const* d_in, const int* in_sizes, int n_in,
                              void* d_out, int out_size, void* d_ws, size_t ws_size,
                              hipStream_t stream) {
    const float* X      = (const float*)d_in[0];
    const float* Xt     = (const float*)d_in[1];
    const float* alphas = (const float*)d_in[2];
    const float* y      = (const float*)d_in[3];
    const float* b      = (const float*)d_in[4];
    float* out = (float*)d_out;

    const int N = in_sizes[0] / D;   // 8192
    const int M = in_sizes[1] / D;   // 8192

    // workspace: bf16 A (N*512B) | packed B (M*512B) | srow[N] | tcol[M] | coef[M]
    char* ws = (char*)d_ws;
    unsigned short* Abf = (unsigned short*)ws;
    char* Bws  = ws + (size_t)N * 512;
    float* srow = (float*)(Bws + (size_t)M * 512);
    float* tcol = srow + N;
    float* coef = tcol + M;

    prep_all_kernel<<<(N + M) / 4, 256, 0, stream>>>(X, Xt, alphas, y, b,
                                                     Abf, Bws, srow, tcol, coef,
                                                     out, N, M);

    dim3 grid(N / BM, JSPLIT);   // 64 x 8 = 512 blocks = 2 per CU
    svm_main_kernel<<<grid, 256, 0, stream>>>(Abf, Bws, srow, tcol, coef, out, M);
}

// Round 15
// 55.899 us; speedup vs baseline: 3.2994x; 3.2994x over previous
//
#include <hip/hip_runtime.h>

typedef __attribute__((ext_vector_type(8))) short bf16x8;
typedef __attribute__((ext_vector_type(4))) float f32x4;

#define GAMMA_ 0.5f
#define LOG2E_ 1.4426950408889634f

constexpr int D      = 256;   // feature dim (K)
constexpr int BM     = 128;   // rows of X per block (2 row-groups of 64)
constexpr int JSPLIT = 8;     // split of M across blockIdx.y

// LDS layout (bytes):
//   [0, 65536)      : per-wave B rings, wave w at [w*16384, +16K): 4 slots x 4KB
//   [65536, 69632)  : tcol panel (1024 x f32)
//   [69632, 73728)  : coef panel (1024 x f32)
//   [73728, 74240)  : srow panel (128 x f32)
constexpr int AUX_TCOL  = 65536;
constexpr int AUX_COEF  = 69632;
constexpr int AUX_SROW  = 73728;
constexpr int LDS_BYTES = 74240;

// ---------- helpers ----------
__device__ __forceinline__ unsigned short f2bf(float f) {
    unsigned int x = __float_as_uint(f);
    x += 0x7FFFu + ((x >> 16) & 1u);          // RNE
    return (unsigned short)(x >> 16);
}

__device__ __forceinline__ void gload16(void* lds, const void* g) {
    __builtin_amdgcn_global_load_lds(
        (const __attribute__((address_space(1))) void*)g,
        (__attribute__((address_space(3))) void*)lds, 16, 0, 0);
}

// ---------- prep ----------
// A rows: linear bf16 [row][k].  B rows: packed DMA/MFMA-native layout:
//   stage block (gjt,kt,wc) = 4KB at ((gjt*4+kt)*2+wc)*4096, inside:
//   chunk c = ni*2+ks (1KB), element (hi*16+lo)*16 + half*8
//   holding bf16x8 of (col = gjt*64+wc*32+ni*16+lo, k = kt*64+ks*32+hi*8..+8)
__global__ void prep_all_kernel(const float* __restrict__ X,
                                const float* __restrict__ Xt,
                                const float* __restrict__ alphas,
                                const float* __restrict__ y,
                                const float* __restrict__ b,
                                unsigned short* __restrict__ Abf,
                                char* __restrict__ Bws,
                                float* __restrict__ srow,
                                float* __restrict__ tcol,
                                float* __restrict__ coef,
                                float* __restrict__ out,
                                int N, int M) {
    int w = threadIdx.x >> 6;         // one wave per row
    int l = threadIdx.x & 63;
    int row = blockIdx.x * 4 + w;
    if (row >= N + M) return;

    const float* src = (row < N) ? X + (size_t)row * D
                                 : Xt + (size_t)(row - N) * D;
    const float4 v = reinterpret_cast<const float4*>(src)[l];
    ushort4 u;
    u.x = f2bf(v.x); u.y = f2bf(v.y); u.z = f2bf(v.z); u.w = f2bf(v.w);

    if (row < N) {
        reinterpret_cast<ushort4*>(Abf + (size_t)row * D)[l] = u;
    } else {
        int r2  = row - N;
        int gjt = r2 >> 6, wcp = (r2 >> 5) & 1, nip = (r2 >> 4) & 1, lop = r2 & 15;
        int ktp = l >> 4, ksp = (l >> 3) & 1, hip = (l >> 1) & 3, half = l & 1;
        size_t dst = ((size_t)(gjt * 4 + ktp) * 2 + wcp) * 4096
                   + (size_t)(nip * 2 + ksp) * 1024 + (hip * 16 + lop) * 16
                   + half * 8;
        *reinterpret_cast<ushort4*>(Bws + dst) = u;
    }

    float ss = v.x * v.x + v.y * v.y + v.z * v.z + v.w * v.w;
    #pragma unroll
    for (int off = 32; off >= 1; off >>= 1) ss += __shfl_xor(ss, off);
    if (l == 0) {
        float folded = -GAMMA_ * LOG2E_ * ss;
        if (row < N) { srow[row] = folded; out[row] = b[0]; }
        else {
            int r2 = row - N;
            tcol[r2] = folded;
            coef[r2] = alphas[r2] * y[r2];
        }
    }
}

// ---------- fused RBF-SVM predict: linear-DMA wave-private pipeline ----------
// pred_i = sum_j exp2( s_i + t_j + (2*g*log2e) * <x_i, xt_j> ) * coef_j + b
// Wave (wr,wc): rows [wr*64,+64), cols = wc-half of each 64-col tile.
// B pre-packed so each stage is ONE contiguous 4KB block: linear DMA source,
// linear LDS dest, ds_read = base + l*16 (+imm) -> no swizzle, no conflicts.
// 4-slot ring, 3 stages in flight, counted vmcnt(12), NO barriers in loop.
// ALL areg indices are compile-time literals (rule #20: no runtime kt).
__launch_bounds__(256, 2)
__global__ void svm_main_kernel(const unsigned short* __restrict__ Abf,
                                const char* __restrict__ Bws,
                                const float* __restrict__ srow,
                                const float* __restrict__ tcol,
                                const float* __restrict__ coef,
                                float* __restrict__ out,
                                int M) {
    __shared__ char L[LDS_BYTES];

    const int tid = threadIdx.x;
    const int w   = tid >> 6;          // wave 0..3
    const int l   = tid & 63;
    const int wr  = w >> 1;            // row group 0..1
    const int wc  = w & 1;             // col half 0..1 (wave-private cols)
    const int hi  = l >> 4;            // 0..3
    const int lo  = l & 15;
    const int row0   = blockIdx.x * BM;
    const int jspan  = M / JSPLIT;     // 1024
    const int jbase  = blockIdx.y * jspan;
    const int JT     = jspan / 64;     // 16 j-tiles (4 stages each)

    // ---- aux staging (shared; drained before the loop) ----
    gload16(L + AUX_TCOL + w * 1024, (const char*)(tcol + jbase) + tid * 16);
    gload16(L + AUX_COEF + w * 1024, (const char*)(coef + jbase) + tid * 16);
    if (w == 0 && l < 32)
        gload16(L + AUX_SROW, (const char*)(srow + row0) + l * 16);

    // ---- A strip into registers (held whole kernel) ----
    const char* Ab = (const char*)Abf;
    bf16x8 areg[4][8];
    #pragma unroll
    for (int mi = 0; mi < 4; ++mi) {
        int row = row0 + wr * 64 + mi * 16 + lo;
        #pragma unroll
        for (int kg = 0; kg < 8; ++kg)
            areg[mi][kg] = *(const bf16x8*)(Ab + (size_t)row * 512 + kg * 64 + hi * 16);
    }

    asm volatile("s_waitcnt vmcnt(0)" ::: "memory");   // drain ALL pre-loop VMEM
    __builtin_amdgcn_s_barrier();                      // aux visible; last barrier

    // per-lane row constants from LDS aux
    float sreg[4][4];
    #pragma unroll
    for (int mi = 0; mi < 4; ++mi)
        #pragma unroll
        for (int r = 0; r < 4; ++r)
            sreg[mi][r] = *(const float*)(L + AUX_SROW
                            + (wr * 64 + mi * 16 + hi * 4 + r) * 4);

    // ---- wave-private B ring: stage = contiguous 4KB, 4 linear gload16 ----
    const char* Bst = Bws + ((size_t)(jbase >> 6) * 8) * 4096 + (size_t)wc * 4096;
    const int   ring0 = w * 16384;
    // stage s: src linear, dst slot = s&3 (passed as literal SL by callers)
    auto issueB = [&](int s, int SL) {
        const char* src = Bst + (size_t)s * 8192 + l * 16;
        char* dst = L + ring0 + SL * 4096;             // wave-uniform base
        #pragma unroll
        for (int c = 0; c < 4; ++c)
            gload16(dst + c * 1024, src + c * 1024);
    };
    issueB(0, 0);
    issueB(1, 1);
    issueB(2, 2);   // 12 outstanding (3 stages deep)

    float partial[4][4];
    #pragma unroll
    for (int mi = 0; mi < 4; ++mi)
        #pragma unroll
        for (int r = 0; r < 4; ++r) partial[mi][r] = 0.0f;

    const float K2G = 2.0f * GAMMA_ * LOG2E_;
    const int cb0 = wc * 32;
    f32x4 acc[4][2];

// one stage, ALL register indices literal. KT = kt (0..3); slot = KT;
// issue target slot = (KT+3)&3, also literal.
#define STAGE(KT, DO_ISSUE, WAITSTR)                                           \
    {                                                                          \
        if (DO_ISSUE) issueB(jt * 4 + (KT) + 3, ((KT) + 3) & 3);               \
        asm volatile(WAITSTR ::: "memory");                                    \
        const char* p = L + ring0 + (KT) * 4096 + l * 16;                      \
        bf16x8 bb00 = *(const bf16x8*)(p);                                     \
        bf16x8 bb01 = *(const bf16x8*)(p + 1024);                              \
        bf16x8 bb10 = *(const bf16x8*)(p + 2048);                              \
        bf16x8 bb11 = *(const bf16x8*)(p + 3072);                              \
        __builtin_amdgcn_s_setprio(1);                                         \
        _Pragma("unroll")                                                      \
        for (int mi = 0; mi < 4; ++mi) {                                       \
            acc[mi][0] = __builtin_amdgcn_mfma_f32_16x16x32_bf16(              \
                areg[mi][(KT) * 2 + 0], bb00, acc[mi][0], 0, 0, 0);            \
            acc[mi][1] = __builtin_amdgcn_mfma_f32_16x16x32_bf16(              \
                areg[mi][(KT) * 2 + 0], bb10, acc[mi][1], 0, 0, 0);            \
        }                                                                      \
        _Pragma("unroll")                                                      \
        for (int mi = 0; mi < 4; ++mi) {                                       \
            acc[mi][0] = __builtin_amdgcn_mfma_f32_16x16x32_bf16(              \
                areg[mi][(KT) * 2 + 1], bb01, acc[mi][0], 0, 0, 0);            \
            acc[mi][1] = __builtin_amdgcn_mfma_f32_16x16x32_bf16(              \
                areg[mi][(KT) * 2 + 1], bb11, acc[mi][1], 0, 0, 0);            \
        }                                                                      \
        __builtin_amdgcn_s_setprio(0);                                         \
    }

#define ACC_INIT                                                               \
    {                                                                          \
        _Pragma("unroll")                                                      \
        for (int mi = 0; mi < 4; ++mi)                                         \
            _Pragma("unroll")                                                  \
            for (int ni = 0; ni < 2; ++ni) {                                   \
                f32x4 z = {0.f, 0.f, 0.f, 0.f};                                \
                acc[mi][ni] = z;                                               \
            }                                                                  \
    }

#define EPILOGUE(JT_)                                                          \
    {                                                                          \
        _Pragma("unroll")                                                      \
        for (int ni = 0; ni < 2; ++ni) {                                       \
            int cl = (JT_) * 64 + cb0 + ni * 16 + lo;                          \
            float t  = *(const float*)(L + AUX_TCOL + cl * 4);                 \
            float cf = *(const float*)(L + AUX_COEF + cl * 4);                 \
            _Pragma("unroll")                                                  \
            for (int mi = 0; mi < 4; ++mi) {                                   \
                _Pragma("unroll")                                              \
                for (int r = 0; r < 4; ++r) {                                  \
                    float arg = fmaf(acc[mi][ni][r], K2G, sreg[mi][r] + t);    \
                    float p2 = __builtin_amdgcn_exp2f(arg);                    \
                    partial[mi][r] = fmaf(p2, cf, partial[mi][r]);             \
                }                                                              \
            }                                                                  \
        }                                                                      \
    }

    for (int jt = 0; jt + 1 < JT; ++jt) {
        ACC_INIT;
        STAGE(0, true, "s_waitcnt vmcnt(12)");
        STAGE(1, true, "s_waitcnt vmcnt(12)");
        STAGE(2, true, "s_waitcnt vmcnt(12)");
        STAGE(3, true, "s_waitcnt vmcnt(12)");
        EPILOGUE(jt);
    }
    {   // last j-tile: drain the ring
        const int jt = JT - 1;
        ACC_INIT;
        STAGE(0, true,  "s_waitcnt vmcnt(12)");   // issues stage NS-1
        STAGE(1, false, "s_waitcnt vmcnt(8)");
        STAGE(2, false, "s_waitcnt vmcnt(4)");
        STAGE(3, false, "s_waitcnt vmcnt(0)");
        EPILOGUE(jt);
    }
#undef STAGE
#undef ACC_INIT
#undef EPILOGUE

    // ---- reduce across the 16 lanes of each row group, one atomic per row ----
    #pragma unroll
    for (int mi = 0; mi < 4; ++mi) {
        #pragma unroll
        for (int r = 0; r < 4; ++r) {
            float v = partial[mi][r];
            v += __shfl_xor(v, 1);
            v += __shfl_xor(v, 2);
            v += __shfl_xor(v, 4);
            v += __shfl_xor(v, 8);
            if (lo == 0) {
                int rowg = row0 + wr * 64 + mi * 16 + hi * 4 + r;
                atomicAdd(&out[rowg], v);
            }
        }
    }
}

// ---------- launcher ----------
extern "C" void kernel_launch(void* const* d_in, const int* in_sizes, int n_in,
                              void* d_out, int out_size, void* d_ws, size_t ws_size,
                              hipStream_t stream) {
    const float* X      = (const float*)d_in[0];
    const float* Xt     = (const float*)d_in[1];
    const float* alphas = (const float*)d_in[2];
    const float* y      = (const float*)d_in[3];
    const float* b      = (const float*)d_in[4];
    float* out = (float*)d_out;

    const int N = in_sizes[0] / D;   // 8192
    const int M = in_sizes[1] / D;   // 8192

    // workspace: bf16 A (N*512B) | packed B (M*512B) | srow[N] | tcol[M] | coef[M]
    char* ws = (char*)d_ws;
    unsigned short* Abf = (unsigned short*)ws;
    char* Bws  = ws + (size_t)N * 512;
    float* srow = (float*)(Bws + (size_t)M * 512);
    float* tcol = srow + N;
    float* coef = tcol + M;

    prep_all_kernel<<<(N + M) / 4, 256, 0, stream>>>(X, Xt, alphas, y, b,
                                                     Abf, Bws, srow, tcol, coef,
                                                     out, N, M);

    dim3 grid(N / BM, JSPLIT);   // 64 x 8 = 512 blocks = 2 per CU
    svm_main_kernel<<<grid, 256, 0, stream>>>(Abf, Bws, srow, tcol, coef, out, M);
}